// Round 1
// baseline (1536.401 us; speedup 1.0000x reference)
//
#include <hip/hip_runtime.h>
#include <hip/hip_bf16.h>

#define N_NODES 100000
#define FDIM    512
#define N_EDGES 3200000

typedef __attribute__((ext_vector_type(8))) short short8;          // 8 bf16 = 4 VGPRs (MFMA A/B frag)
typedef __attribute__((ext_vector_type(8))) unsigned short ushort8;
typedef __attribute__((ext_vector_type(4))) unsigned short ushort4_t;
typedef __attribute__((ext_vector_type(4))) float floatx4;

__device__ __forceinline__ unsigned short f2bf(float f) {
    unsigned u = __float_as_uint(f);
    u += 0x7FFFu + ((u >> 16) & 1u);      // round-to-nearest-even
    return (unsigned short)(u >> 16);
}
__device__ __forceinline__ float bf2f(unsigned short u) {
    return __uint_as_float(((unsigned)u) << 16);
}

// ---- 1. weight fp32 [K][N] -> bf16 transposed [N][K] ----
__global__ __launch_bounds__(256) void convert_w_k(const float* __restrict__ W,
                                                   unsigned short* __restrict__ Wt) {
    int idx = blockIdx.x * 256 + threadIdx.x;   // 0 .. 512*512-1
    int k = idx >> 9, n = idx & 511;
    Wt[n * 512 + k] = f2bf(W[idx]);
}

// ---- 2. zero per-row counters ----
__global__ __launch_bounds__(256) void zero_counts_k(int* __restrict__ counts) {
    int i = blockIdx.x * 256 + threadIdx.x;
    if (i < N_NODES) counts[i] = 0;
}

// ---- 3. histogram of edge rows ----
__global__ __launch_bounds__(256) void hist_k(const int* __restrict__ row,
                                              int* __restrict__ counts) {
    int i = blockIdx.x * 256 + threadIdx.x;
    if (i < N_EDGES) atomicAdd(&counts[row[i]], 1);
}

// ---- 4. exclusive scan over counts (single block, 1024 threads) ----
__global__ __launch_bounds__(1024) void scan_k(const int* __restrict__ counts,
                                               int* __restrict__ row_start,
                                               int* __restrict__ cursor) {
    __shared__ int sm[1024];
    __shared__ int carry;
    int tid = threadIdx.x;
    if (tid == 0) carry = 0;
    __syncthreads();
    for (int base = 0; base < N_NODES; base += 1024) {
        int i = base + tid;
        int v = (i < N_NODES) ? counts[i] : 0;
        int c0 = carry;
        sm[tid] = v;
        __syncthreads();
        #pragma unroll
        for (int off = 1; off < 1024; off <<= 1) {
            int t = (tid >= off) ? sm[tid - off] : 0;
            __syncthreads();
            sm[tid] += t;
            __syncthreads();
        }
        int incl  = sm[tid];
        int total = sm[1023];
        int excl  = c0 + incl - v;
        if (i < N_NODES) { row_start[i] = excl; cursor[i] = excl; }
        __syncthreads();
        if (tid == 0) carry = c0 + total;
        __syncthreads();
    }
    if (tid == 0) row_start[N_NODES] = carry;   // == N_EDGES
}

// ---- 5. scatter edges into row-sorted (col, val) pairs ----
__global__ __launch_bounds__(256) void scatter_k(const int* __restrict__ row,
                                                 const int* __restrict__ col,
                                                 const float* __restrict__ val,
                                                 int* __restrict__ cursor,
                                                 int2* __restrict__ edges) {
    int i = blockIdx.x * 256 + threadIdx.x;
    if (i < N_EDGES) {
        int r = row[i];
        int pos = atomicAdd(&cursor[r], 1);
        edges[pos] = make_int2(col[i], __float_as_int(val[i]));
    }
}

// ---- 6. GEMM: support[M][N] (bf16) = features[M][K] (fp32->bf16) @ Wt^T ----
// block = 256 thr (4 waves), tile BM=64 BN=64 BK=32; wave w -> 32x32 subtile (2x2 MFMAs)
__global__ __launch_bounds__(256) void gemm_k(const float* __restrict__ A,
                                              const unsigned short* __restrict__ Bt,  // [N][K] bf16
                                              unsigned short* __restrict__ C) {       // [M][N] bf16
    const int baseN = blockIdx.x * 64;
    const int baseM = blockIdx.y * 64;
    const int tid  = threadIdx.x;
    const int lane = tid & 63, wave = tid >> 6;
    const int wm = (wave & 1) * 32;          // wave M offset in tile
    const int wn = (wave >> 1) * 32;         // wave N offset in tile
    const int lrow = lane & 15, quad = lane >> 4;

    __shared__ unsigned short As[64][40];    // [m][k], pad 32->40 (stride 80B: 2-way banks, free)
    __shared__ unsigned short Bs[64][40];    // [n][k]

    floatx4 acc[2][2] = {};

    const int ar = tid >> 3, akg = tid & 7;  // A staging: row ar/ar+32, float4 group akg
    const int bn = tid >> 2, bkg = tid & 3;  // B staging: n-row bn, 16B group bkg

    for (int k0 = 0; k0 < FDIM; k0 += 32) {
        // stage A (fp32 -> bf16), 64 rows x 32 k
        #pragma unroll
        for (int p = 0; p < 2; ++p) {
            int r = ar + p * 32;
            int gr = baseM + r;
            float4 f = make_float4(0.f, 0.f, 0.f, 0.f);
            if (gr < N_NODES)
                f = *((const float4*)(A + (size_t)gr * FDIM + k0) + akg);
            ushort4_t u = { f2bf(f.x), f2bf(f.y), f2bf(f.z), f2bf(f.w) };
            *(ushort4_t*)(&As[r][akg * 4]) = u;
        }
        // stage B (already bf16, [n][k] layout matches)
        {
            ushort8 b = *(const ushort8*)(Bt + (size_t)(baseN + bn) * FDIM + k0 + bkg * 8);
            *(ushort8*)(&Bs[bn][bkg * 8]) = b;
        }
        __syncthreads();

        short8 a0 = *(const short8*)(&As[wm + lrow][quad * 8]);
        short8 a1 = *(const short8*)(&As[wm + 16 + lrow][quad * 8]);
        short8 b0 = *(const short8*)(&Bs[wn + lrow][quad * 8]);
        short8 b1 = *(const short8*)(&Bs[wn + 16 + lrow][quad * 8]);

        acc[0][0] = __builtin_amdgcn_mfma_f32_16x16x32_bf16(a0, b0, acc[0][0], 0, 0, 0);
        acc[0][1] = __builtin_amdgcn_mfma_f32_16x16x32_bf16(a0, b1, acc[0][1], 0, 0, 0);
        acc[1][0] = __builtin_amdgcn_mfma_f32_16x16x32_bf16(a1, b0, acc[1][0], 0, 0, 0);
        acc[1][1] = __builtin_amdgcn_mfma_f32_16x16x32_bf16(a1, b1, acc[1][1], 0, 0, 0);

        __syncthreads();
    }

    // epilogue: C/D layout col=lane&15, row=quad*4+reg
    #pragma unroll
    for (int mi = 0; mi < 2; ++mi)
        #pragma unroll
        for (int ni = 0; ni < 2; ++ni)
            #pragma unroll
            for (int rr = 0; rr < 4; ++rr) {
                int row = baseM + wm + mi * 16 + quad * 4 + rr;
                int colj = baseN + wn + ni * 16 + lrow;
                if (row < N_NODES)
                    C[(size_t)row * FDIM + colj] = f2bf(acc[mi][ni][rr]);
            }
}

// ---- 7. SpMM + ReLU: one wave per row, lane owns 8 features ----
__global__ __launch_bounds__(64) void spmm_k(const unsigned short* __restrict__ sup,
                                             const int* __restrict__ row_start,
                                             const int2* __restrict__ edges,
                                             float* __restrict__ out) {
    const int r = blockIdx.x;
    const int lane = threadIdx.x;
    const int start = row_start[r], end = row_start[r + 1];

    float acc[8] = {0.f, 0.f, 0.f, 0.f, 0.f, 0.f, 0.f, 0.f};

    int e = start;
    int e4 = start + ((end - start) & ~3);
    for (; e < e4; e += 4) {                         // 4-deep for outstanding gathers
        int2 p0 = edges[e + 0], p1 = edges[e + 1], p2 = edges[e + 2], p3 = edges[e + 3];
        ushort8 s0 = *(const ushort8*)(sup + (size_t)p0.x * FDIM + lane * 8);
        ushort8 s1 = *(const ushort8*)(sup + (size_t)p1.x * FDIM + lane * 8);
        ushort8 s2 = *(const ushort8*)(sup + (size_t)p2.x * FDIM + lane * 8);
        ushort8 s3 = *(const ushort8*)(sup + (size_t)p3.x * FDIM + lane * 8);
        float v0 = __int_as_float(p0.y), v1 = __int_as_float(p1.y);
        float v2 = __int_as_float(p2.y), v3 = __int_as_float(p3.y);
        #pragma unroll
        for (int i = 0; i < 8; ++i) {
            acc[i] += v0 * bf2f((unsigned short)s0[i]);
            acc[i] += v1 * bf2f((unsigned short)s1[i]);
            acc[i] += v2 * bf2f((unsigned short)s2[i]);
            acc[i] += v3 * bf2f((unsigned short)s3[i]);
        }
    }
    for (; e < end; ++e) {
        int2 p = edges[e];
        ushort8 s = *(const ushort8*)(sup + (size_t)p.x * FDIM + lane * 8);
        float v = __int_as_float(p.y);
        #pragma unroll
        for (int i = 0; i < 8; ++i) acc[i] += v * bf2f((unsigned short)s[i]);
    }

    float* op = out + (size_t)r * FDIM + lane * 8;
    *(float4*)op = make_float4(fmaxf(acc[0], 0.f), fmaxf(acc[1], 0.f),
                               fmaxf(acc[2], 0.f), fmaxf(acc[3], 0.f));
    *(float4*)(op + 4) = make_float4(fmaxf(acc[4], 0.f), fmaxf(acc[5], 0.f),
                                     fmaxf(acc[6], 0.f), fmaxf(acc[7], 0.f));
}

extern "C" void kernel_launch(void* const* d_in, const int* in_sizes, int n_in,
                              void* d_out, int out_size, void* d_ws, size_t ws_size,
                              hipStream_t stream) {
    const float* features = (const float*)d_in[0];
    const float* weight   = (const float*)d_in[1];
    const int*   edge_row = (const int*)d_in[2];
    const int*   edge_col = (const int*)d_in[3];
    const float* edge_val = (const float*)d_in[4];
    float* out = (float*)d_out;

    char* ws = (char*)d_ws;
    size_t off = 0;
    unsigned short* sup = (unsigned short*)(ws + off); off += (size_t)N_NODES * FDIM * 2;  // 102.4 MB
    unsigned short* Wt  = (unsigned short*)(ws + off); off += (size_t)FDIM * FDIM * 2;     // 0.5 MB
    int* counts    = (int*)(ws + off); off += 400128;
    int* row_start = (int*)(ws + off); off += 400128;
    int* cursor    = (int*)(ws + off); off += 400128;
    int2* edges    = (int2*)(ws + off); off += (size_t)N_EDGES * 8;                        // 25.6 MB
    // total ~129.7 MB

    convert_w_k<<<dim3((FDIM * FDIM) / 256), dim3(256), 0, stream>>>(weight, Wt);
    zero_counts_k<<<dim3((N_NODES + 255) / 256), dim3(256), 0, stream>>>(counts);
    hist_k<<<dim3(N_EDGES / 256), dim3(256), 0, stream>>>(edge_row, counts);
    scan_k<<<dim3(1), dim3(1024), 0, stream>>>(counts, row_start, cursor);
    scatter_k<<<dim3(N_EDGES / 256), dim3(256), 0, stream>>>(edge_row, edge_col, edge_val,
                                                             cursor, edges);
    gemm_k<<<dim3(FDIM / 64, (N_NODES + 63) / 64), dim3(256), 0, stream>>>(features, Wt, sup);
    spmm_k<<<dim3(N_NODES), dim3(64), 0, stream>>>(sup, row_start, edges, out);
}

// Round 2
// 1376.084 us; speedup vs baseline: 1.1165x; 1.1165x over previous
//
#include <hip/hip_runtime.h>
#include <hip/hip_bf16.h>

#define N_NODES 100000
#define FDIM    512
#define N_EDGES 3200000
#define SCAN_BLOCKS 98   // ceil(100000/1024)

typedef __attribute__((ext_vector_type(8))) short short8;          // 8 bf16 = 4 VGPRs (MFMA A/B frag)
typedef __attribute__((ext_vector_type(8))) unsigned short ushort8;
typedef __attribute__((ext_vector_type(4))) unsigned short ushort4_t;
typedef __attribute__((ext_vector_type(4))) float floatx4;

__device__ __forceinline__ unsigned short f2bf(float f) {
    unsigned u = __float_as_uint(f);
    u += 0x7FFFu + ((u >> 16) & 1u);      // round-to-nearest-even
    return (unsigned short)(u >> 16);
}
__device__ __forceinline__ float bf2f(unsigned short u) {
    return __uint_as_float(((unsigned)u) << 16);
}

// ---- 1. weight fp32 [K][N] -> bf16 transposed [N][K] ----
__global__ __launch_bounds__(256) void convert_w_k(const float* __restrict__ W,
                                                   unsigned short* __restrict__ Wt) {
    int idx = blockIdx.x * 256 + threadIdx.x;   // 0 .. 512*512-1
    int k = idx >> 9, n = idx & 511;
    Wt[n * 512 + k] = f2bf(W[idx]);
}

// ---- 2. zero per-row counters ----
__global__ __launch_bounds__(256) void zero_counts_k(int* __restrict__ counts) {
    int i = blockIdx.x * 256 + threadIdx.x;
    if (i < N_NODES) counts[i] = 0;
}

// ---- 3. histogram of edge rows ----
__global__ __launch_bounds__(256) void hist_k(const int* __restrict__ row,
                                              int* __restrict__ counts) {
    int i = blockIdx.x * 256 + threadIdx.x;
    if (i < N_EDGES) atomicAdd(&counts[row[i]], 1);
}

// ---- 4a. per-block inclusive scan (98 blocks in parallel) ----
__global__ __launch_bounds__(1024) void scan1_k(const int* __restrict__ counts,
                                                int* __restrict__ row_start,
                                                int* __restrict__ bsum) {
    __shared__ int sm[1024];
    const int b = blockIdx.x, tid = threadIdx.x;
    const int i = b * 1024 + tid;
    int v = (i < N_NODES) ? counts[i] : 0;
    sm[tid] = v;
    __syncthreads();
    #pragma unroll
    for (int off = 1; off < 1024; off <<= 1) {
        int t = (tid >= off) ? sm[tid - off] : 0;
        __syncthreads();
        sm[tid] += t;
        __syncthreads();
    }
    if (i < N_NODES) row_start[i] = sm[tid] - v;   // block-local exclusive prefix
    if (tid == 1023) bsum[b] = sm[1023];
}

// ---- 4b. scan the 98 block sums (single small block) ----
__global__ __launch_bounds__(128) void scan2_k(const int* __restrict__ bsum,
                                               int* __restrict__ boffset) {
    __shared__ int sm[128];
    const int tid = threadIdx.x;
    int v = (tid < SCAN_BLOCKS) ? bsum[tid] : 0;
    sm[tid] = v;
    __syncthreads();
    #pragma unroll
    for (int off = 1; off < 128; off <<= 1) {
        int t = (tid >= off) ? sm[tid - off] : 0;
        __syncthreads();
        sm[tid] += t;
        __syncthreads();
    }
    if (tid < SCAN_BLOCKS) boffset[tid] = sm[tid] - v;   // exclusive
}

// ---- 4c. add block offsets, produce row_start + cursor ----
__global__ __launch_bounds__(256) void scan3_k(const int* __restrict__ boffset,
                                               int* __restrict__ row_start,
                                               int* __restrict__ cursor) {
    int i = blockIdx.x * 256 + threadIdx.x;
    if (i < N_NODES) {
        int rs = row_start[i] + boffset[i >> 10];
        row_start[i] = rs;
        cursor[i] = rs;
    }
    if (i == 0) row_start[N_NODES] = N_EDGES;
}

// ---- 5. scatter edges into row-sorted (col, val) pairs ----
__global__ __launch_bounds__(256) void scatter_k(const int* __restrict__ row,
                                                 const int* __restrict__ col,
                                                 const float* __restrict__ val,
                                                 int* __restrict__ cursor,
                                                 int2* __restrict__ edges) {
    int i = blockIdx.x * 256 + threadIdx.x;
    if (i < N_EDGES) {
        int r = row[i];
        int pos = atomicAdd(&cursor[r], 1);
        edges[pos] = make_int2(col[i], __float_as_int(val[i]));
    }
}

// ---- 6. GEMM (m97-rung structure): support[M][N] bf16 = A[M][K] fp32 @ Wt[N][K]^T ----
// 128x128 tile, BK=32, 4 waves, 4x4 16x16 MFMA per wave.
// B staged via global_load_lds width-16 (bf16, unpadded). A staged manually with
// fp32->bf16 convert into padded LDS (row stride 40 shorts = 80B -> 2-way banks, free).
__global__ __launch_bounds__(256) void gemm_k(const float* __restrict__ A,
                                              const unsigned short* __restrict__ Bt,  // [N][K] bf16
                                              unsigned short* __restrict__ C) {       // [M][N] bf16
    const int baseN = blockIdx.x * 128;
    const int baseM = blockIdx.y * 128;
    const int tid  = threadIdx.x;
    const int lane = tid & 63, wave = tid >> 6;
    const int wm = (wave & 1) * 64;
    const int wn = (wave >> 1) * 64;
    const int lrow = lane & 15, quad = lane >> 4;

    __shared__ unsigned short As[128][40];       // padded [m][k]
    __shared__ unsigned short Bs[128 * 32];      // unpadded [n][k], global_load_lds dest

    floatx4 acc[4][4] = {};

    for (int k0 = 0; k0 < FDIM; k0 += 32) {
        // B: 8KB via async global->LDS, 2 x 16B per thread (LDS dest = uniform base + lane*16)
        #pragma unroll
        for (int i = 0; i < 2; ++i) {
            int ofs = i * 4096 + tid * 16;       // byte offset in Bs
            int row = ofs >> 6;                  // 64B per row
            int ke  = (ofs & 63) >> 1;           // element offset in row
            __builtin_amdgcn_global_load_lds(
                (const __attribute__((address_space(1))) void*)
                    (Bt + (size_t)(baseN + row) * FDIM + k0 + ke),
                (__attribute__((address_space(3))) void*)((char*)Bs + ofs),
                16, 0, 0);
        }
        // A: 128x32 fp32 -> bf16, flat float4 index (coalesced 16B/lane)
        #pragma unroll
        for (int i = 0; i < 4; ++i) {
            int f   = tid + i * 256;             // float4 index within tile
            int row = f >> 3;                    // 8 float4 per row
            int kq  = f & 7;
            int gr  = baseM + row;
            float4 v = make_float4(0.f, 0.f, 0.f, 0.f);
            if (gr < N_NODES)
                v = *(const float4*)(A + (size_t)gr * FDIM + k0 + kq * 4);
            ushort4_t u = { f2bf(v.x), f2bf(v.y), f2bf(v.z), f2bf(v.w) };
            *(ushort4_t*)(&As[row][kq * 4]) = u;
        }
        __syncthreads();

        short8 af[4], bfr[4];
        #pragma unroll
        for (int mi = 0; mi < 4; ++mi)
            af[mi] = *(const short8*)(&As[wm + mi * 16 + lrow][quad * 8]);
        #pragma unroll
        for (int ni = 0; ni < 4; ++ni)
            bfr[ni] = *(const short8*)(&Bs[(wn + ni * 16 + lrow) * 32 + quad * 8]);
        #pragma unroll
        for (int mi = 0; mi < 4; ++mi)
            #pragma unroll
            for (int ni = 0; ni < 4; ++ni)
                acc[mi][ni] = __builtin_amdgcn_mfma_f32_16x16x32_bf16(
                    af[mi], bfr[ni], acc[mi][ni], 0, 0, 0);
        __syncthreads();
    }

    // epilogue: C/D layout col=lane&15, row=quad*4+reg
    #pragma unroll
    for (int mi = 0; mi < 4; ++mi)
        #pragma unroll
        for (int ni = 0; ni < 4; ++ni)
            #pragma unroll
            for (int rr = 0; rr < 4; ++rr) {
                int row  = baseM + wm + mi * 16 + quad * 4 + rr;
                int colj = baseN + wn + ni * 16 + lrow;
                if (row < N_NODES)
                    C[(size_t)row * FDIM + colj] = f2bf(acc[mi][ni][rr]);
            }
}

// ---- 7. SpMM + ReLU: one wave per row, lane owns 8 features (unchanged) ----
__global__ __launch_bounds__(64) void spmm_k(const unsigned short* __restrict__ sup,
                                             const int* __restrict__ row_start,
                                             const int2* __restrict__ edges,
                                             float* __restrict__ out) {
    const int r = blockIdx.x;
    const int lane = threadIdx.x;
    const int start = row_start[r], end = row_start[r + 1];

    float acc[8] = {0.f, 0.f, 0.f, 0.f, 0.f, 0.f, 0.f, 0.f};

    int e = start;
    int e4 = start + ((end - start) & ~3);
    for (; e < e4; e += 4) {
        int2 p0 = edges[e + 0], p1 = edges[e + 1], p2 = edges[e + 2], p3 = edges[e + 3];
        ushort8 s0 = *(const ushort8*)(sup + (size_t)p0.x * FDIM + lane * 8);
        ushort8 s1 = *(const ushort8*)(sup + (size_t)p1.x * FDIM + lane * 8);
        ushort8 s2 = *(const ushort8*)(sup + (size_t)p2.x * FDIM + lane * 8);
        ushort8 s3 = *(const ushort8*)(sup + (size_t)p3.x * FDIM + lane * 8);
        float v0 = __int_as_float(p0.y), v1 = __int_as_float(p1.y);
        float v2 = __int_as_float(p2.y), v3 = __int_as_float(p3.y);
        #pragma unroll
        for (int i = 0; i < 8; ++i) {
            acc[i] += v0 * bf2f((unsigned short)s0[i]);
            acc[i] += v1 * bf2f((unsigned short)s1[i]);
            acc[i] += v2 * bf2f((unsigned short)s2[i]);
            acc[i] += v3 * bf2f((unsigned short)s3[i]);
        }
    }
    for (; e < end; ++e) {
        int2 p = edges[e];
        ushort8 s = *(const ushort8*)(sup + (size_t)p.x * FDIM + lane * 8);
        float v = __int_as_float(p.y);
        #pragma unroll
        for (int i = 0; i < 8; ++i) acc[i] += v * bf2f((unsigned short)s[i]);
    }

    float* op = out + (size_t)r * FDIM + lane * 8;
    *(float4*)op = make_float4(fmaxf(acc[0], 0.f), fmaxf(acc[1], 0.f),
                               fmaxf(acc[2], 0.f), fmaxf(acc[3], 0.f));
    *(float4*)(op + 4) = make_float4(fmaxf(acc[4], 0.f), fmaxf(acc[5], 0.f),
                                     fmaxf(acc[6], 0.f), fmaxf(acc[7], 0.f));
}

extern "C" void kernel_launch(void* const* d_in, const int* in_sizes, int n_in,
                              void* d_out, int out_size, void* d_ws, size_t ws_size,
                              hipStream_t stream) {
    const float* features = (const float*)d_in[0];
    const float* weight   = (const float*)d_in[1];
    const int*   edge_row = (const int*)d_in[2];
    const int*   edge_col = (const int*)d_in[3];
    const float* edge_val = (const float*)d_in[4];
    float* out = (float*)d_out;

    char* ws = (char*)d_ws;
    size_t off = 0;
    unsigned short* sup = (unsigned short*)(ws + off); off += (size_t)N_NODES * FDIM * 2;  // 102.4 MB
    unsigned short* Wt  = (unsigned short*)(ws + off); off += (size_t)FDIM * FDIM * 2;     // 0.5 MB
    int* counts    = (int*)(ws + off); off += 400128;
    int* row_start = (int*)(ws + off); off += 400128;
    int* cursor    = (int*)(ws + off); off += 400128;
    int* bsum      = (int*)(ws + off); off += 512;
    int* boffset   = (int*)(ws + off); off += 512;
    int2* edges    = (int2*)(ws + off); off += (size_t)N_EDGES * 8;                        // 25.6 MB
    // total ~130 MB

    convert_w_k<<<dim3((FDIM * FDIM) / 256), dim3(256), 0, stream>>>(weight, Wt);
    zero_counts_k<<<dim3((N_NODES + 255) / 256), dim3(256), 0, stream>>>(counts);
    hist_k<<<dim3(N_EDGES / 256), dim3(256), 0, stream>>>(edge_row, counts);
    scan1_k<<<dim3(SCAN_BLOCKS), dim3(1024), 0, stream>>>(counts, row_start, bsum);
    scan2_k<<<dim3(1), dim3(128), 0, stream>>>(bsum, boffset);
    scan3_k<<<dim3((N_NODES + 255) / 256), dim3(256), 0, stream>>>(boffset, row_start, cursor);
    scatter_k<<<dim3(N_EDGES / 256), dim3(256), 0, stream>>>(edge_row, edge_col, edge_val,
                                                             cursor, edges);
    gemm_k<<<dim3(FDIM / 128, (N_NODES + 127) / 128), dim3(256), 0, stream>>>(features, Wt, sup);
    spmm_k<<<dim3(N_NODES), dim3(64), 0, stream>>>(sup, row_start, edges, out);
}